// Round 1
// baseline (236.804 us; speedup 1.0000x reference)
//
#include <hip/hip_runtime.h>

// Problem constants (fixed by setup_inputs)
#define B_   16
#define N_   262144            // 2^18 pixels per image
#define NC   150               // classes
#define NP   4096              // pred segment ids
#define T_   (B_ * NC)         // 2400 distinct target ids
#define TOTAL (B_ * N_)        // 4,194,304 pixels

// ---------------------------------------------------------------------------
// Kernel 1: co-occurrence histogram O[p][t], t = b*NC + class
// ---------------------------------------------------------------------------
__global__ __launch_bounds__(256) void hist_kernel(const int* __restrict__ pred,
                                                   const int* __restrict__ tgt,
                                                   unsigned int* __restrict__ O) {
    int stride = gridDim.x * blockDim.x;
    for (int i = blockIdx.x * blockDim.x + threadIdx.x; i < TOTAL; i += stride) {
        int p = pred[i];
        int b = i >> 18;                 // N_ = 2^18
        int t = b * NC + tgt[i];
        atomicAdd(&O[(size_t)p * T_ + t], 1u);
    }
}

// ---------------------------------------------------------------------------
// Kernel 2: column sums n_tgt[t] = sum_p O[p][t]
// grid.x covers columns in chunks of 64, grid.y slices rows.
// Consecutive lanes read consecutive columns -> coalesced.
// ---------------------------------------------------------------------------
__global__ __launch_bounds__(256) void colsum_kernel(const unsigned int* __restrict__ O,
                                                     unsigned int* __restrict__ n_tgt) {
    int c = blockIdx.x * 64 + (threadIdx.x & 63);
    int rbase = blockIdx.y * (NP / 8) + (threadIdx.x >> 6);  // 512 rows per slice, 4 row-lanes
    unsigned int s = 0;
    if (c < T_) {
        for (int r = rbase; r < blockIdx.y * (NP / 8) + (NP / 8); r += 4) {
            s += O[(size_t)r * T_ + c];
        }
        atomicAdd(&n_tgt[c], s);
    }
}

// ---------------------------------------------------------------------------
// Kernel 3: per pred-id p — row sum (n_pred), IoU fold over batch,
// matmul with targets, row-normalize. One 256-thread block per p.
// ---------------------------------------------------------------------------
__global__ __launch_bounds__(256) void iou_kernel(const unsigned int* __restrict__ O,
                                                  const unsigned int* __restrict__ n_tgt,
                                                  const float* __restrict__ targets,
                                                  float* __restrict__ out) {
    __shared__ unsigned int row[T_];   // 2400 u32 = 9.6 KB
    __shared__ float iou_pc[NC];
    __shared__ float red[256];

    int p = blockIdx.x;
    const unsigned int* Orow = O + (size_t)p * T_;

    // stage row + partial row-sum (counts are exact integers < 2^24)
    unsigned int s = 0;
    for (int j = threadIdx.x; j < T_; j += 256) {
        unsigned int v = Orow[j];
        row[j] = v;
        s += v;
    }
    red[threadIdx.x] = (float)s;
    __syncthreads();
    for (int off = 128; off > 0; off >>= 1) {
        if (threadIdx.x < off) red[threadIdx.x] += red[threadIdx.x + off];
        __syncthreads();
    }
    float n_pred = red[0];
    __syncthreads();

    int c = threadIdx.x;
    if (c < NC) {
        float acc = 0.f;
        #pragma unroll
        for (int b = 0; b < B_; ++b) {
            unsigned int v = row[b * NC + c];
            if (v) {
                float fv = (float)v;
                acc += fv / (n_pred + (float)n_tgt[b * NC + c] - fv);
            }
        }
        iou_pc[c] = acc;
    }
    __syncthreads();

    // out_c = sum_k iou_pc[k] * targets[k][c]  (targets is eye in practice,
    // but apply the general matmul to honor the parameter)
    float outc = 0.f;
    if (c < NC) {
        for (int k = 0; k < NC; ++k) outc += iou_pc[k] * targets[k * NC + c];
    }
    red[threadIdx.x] = (c < NC) ? outc : 0.f;
    __syncthreads();
    for (int off = 128; off > 0; off >>= 1) {
        if (threadIdx.x < off) red[threadIdx.x] += red[threadIdx.x + off];
        __syncthreads();
    }
    float den = red[0];

    if (c < NC) out[(size_t)p * NC + c] = outc / den;
}

// ---------------------------------------------------------------------------
extern "C" void kernel_launch(void* const* d_in, const int* in_sizes, int n_in,
                              void* d_out, int out_size, void* d_ws, size_t ws_size,
                              hipStream_t stream) {
    const int*   pred    = (const int*)d_in[0];
    const int*   tgt     = (const int*)d_in[1];
    const float* targets = (const float*)d_in[2];
    float*       out     = (float*)d_out;

    unsigned int* O     = (unsigned int*)d_ws;                 // NP*T_ u32 = 39.3 MB
    unsigned int* n_tgt = O + (size_t)NP * T_;                 // 2400 u32

    size_t zero_bytes = ((size_t)NP * T_ + T_) * sizeof(unsigned int);
    hipMemsetAsync(d_ws, 0, zero_bytes, stream);

    hist_kernel<<<2048, 256, 0, stream>>>(pred, tgt, O);
    colsum_kernel<<<dim3(38, 8), 256, 0, stream>>>(O, n_tgt);
    iou_kernel<<<NP, 256, 0, stream>>>(O, n_tgt, targets, out);
}

// Round 2
// 129.837 us; speedup vs baseline: 1.8239x; 1.8239x over previous
//
#include <hip/hip_runtime.h>

// Problem constants (fixed by setup_inputs)
#define B_    16
#define N_    262144            // 2^18 pixels per image
#define NC    150               // classes
#define NP    4096              // pred segment ids
#define T_    (B_ * NC)         // 2400 distinct target ids
#define TOTAL (B_ * N_)         // 4,194,304 pixels

#define BUCKETS      256        // pred>>4
#define PRED_PER_BKT 16
#define CAP          18432      // per-bucket record capacity (avg 16384, +16 sigma)
#define P1_BLOCKS    512
#define P1_PIX       (TOTAL / P1_BLOCKS)   // 8192 pixels per block
#define P1_PER_THR   (P1_PIX / 256)        // 32 per thread

typedef unsigned int u32;
typedef unsigned short u16;

// ---------------------------------------------------------------------------
// Kernel A: n_tgt[t] = # pixels with target id t (t = b*NC + class).
// Pure LDS-privatized histogram over 2400 bins.
// ---------------------------------------------------------------------------
__global__ __launch_bounds__(256) void nt_kernel(const int* __restrict__ tgt,
                                                 u32* __restrict__ gNT) {
    __shared__ u32 h[T_];
    for (int j = threadIdx.x; j < T_; j += 256) h[j] = 0;
    __syncthreads();
    int stride4 = gridDim.x * 256;
    const int4* tgt4 = (const int4*)tgt;
    for (int vi = blockIdx.x * 256 + threadIdx.x; vi < TOTAL / 4; vi += stride4) {
        int4 tv = tgt4[vi];
        int i0 = vi * 4;
        atomicAdd(&h[((i0 + 0) >> 18) * NC + tv.x], 1u);
        atomicAdd(&h[((i0 + 1) >> 18) * NC + tv.y], 1u);
        atomicAdd(&h[((i0 + 2) >> 18) * NC + tv.z], 1u);
        atomicAdd(&h[((i0 + 3) >> 18) * NC + tv.w], 1u);
    }
    __syncthreads();
    for (int j = threadIdx.x; j < T_; j += 256)
        if (h[j]) atomicAdd(&gNT[j], h[j]);
}

// ---------------------------------------------------------------------------
// Kernel B: radix-split pixels into 256 buckets by pred>>4.
// Record = u16 localkey = (p&15)*2400 + (b*150 + cls).
// LDS staging so the global flush is coalesced runs per bucket.
// ---------------------------------------------------------------------------
__global__ __launch_bounds__(256) void partition_kernel(const int* __restrict__ pred,
                                                        const int* __restrict__ tgt,
                                                        u16* __restrict__ records,
                                                        u32* __restrict__ gCount) {
    __shared__ u32 cnt[BUCKETS];
    __shared__ u32 lstart[BUCKETS];
    __shared__ u32 gbase[BUCKETS];
    __shared__ u32 cursor[BUCKETS];
    __shared__ u32 staging[P1_PIX];          // 32 KB

    int tid = threadIdx.x;
    cnt[tid] = 0;
    __syncthreads();

    u32 keys[P1_PER_THR];
    int base = blockIdx.x * P1_PIX;
    const int4* pred4 = (const int4*)pred;
    const int4* tgt4  = (const int4*)tgt;

    #pragma unroll
    for (int k = 0; k < P1_PER_THR / 4; ++k) {
        int vi = (base >> 2) + k * 256 + tid;
        int4 pv = pred4[vi];
        int4 tv = tgt4[vi];
        int i0 = vi * 4;
        int pe[4] = {pv.x, pv.y, pv.z, pv.w};
        int te[4] = {tv.x, tv.y, tv.z, tv.w};
        #pragma unroll
        for (int e = 0; e < 4; ++e) {
            int p = pe[e];
            int t = ((i0 + e) >> 18) * NC + te[e];
            u32 bkt = (u32)(p >> 4);
            keys[k * 4 + e] = (bkt << 16) | (u32)((p & 15) * T_ + t);
            atomicAdd(&cnt[bkt], 1u);
        }
    }
    __syncthreads();

    // exclusive prefix sum over 256 bucket counts (Hillis-Steele)
    lstart[tid] = cnt[tid];
    __syncthreads();
    for (int off = 1; off < BUCKETS; off <<= 1) {
        u32 v = 0;
        if (tid >= off) v = lstart[tid - off];
        __syncthreads();
        if (tid >= off) lstart[tid] += v;
        __syncthreads();
    }
    {
        u32 ex = lstart[tid] - cnt[tid];
        lstart[tid] = ex;
        cursor[tid] = ex;
        gbase[tid]  = atomicAdd(&gCount[tid], cnt[tid]);
    }
    __syncthreads();

    // scatter into LDS staging, sorted by bucket
    #pragma unroll
    for (int k = 0; k < P1_PER_THR; ++k) {
        u32 v = keys[k];
        u32 pos = atomicAdd(&cursor[v >> 16], 1u);
        staging[pos] = v;
    }
    __syncthreads();

    // coalesced flush: consecutive staging entries in a bucket map to
    // consecutive global record slots
    for (int r = tid; r < P1_PIX; r += 256) {
        u32 v = staging[r];
        u32 bkt = v >> 16;
        u32 gpos = gbase[bkt] + ((u32)r - lstart[bkt]);
        if (gpos < CAP) records[(size_t)bkt * CAP + gpos] = (u16)(v & 0xFFFFu);
    }
}

// ---------------------------------------------------------------------------
// Kernel C: one block per bucket. Build 16x2400 histogram in LDS (u16 packed
// in u32 words), row sums -> n_pred, IoU fold over batch, targets matmul,
// row-normalize, write out. O never hits global memory.
// ---------------------------------------------------------------------------
__global__ __launch_bounds__(256) void iou_kernel(const u16* __restrict__ records,
                                                  const u32* __restrict__ gCount,
                                                  const u32* __restrict__ gNT,
                                                  const float* __restrict__ targets,
                                                  float* __restrict__ out) {
    __shared__ u32 hist[PRED_PER_BKT * T_ / 2];   // 19200 words = 76.8 KB
    __shared__ u32 nt_s[T_];                      // 9.6 KB
    __shared__ float npred_s[PRED_PER_BKT];
    __shared__ float iou_pc[PRED_PER_BKT][NC];    // 9.6 KB
    __shared__ float red[256];

    int tid = threadIdx.x, bkt = blockIdx.x;
    for (int j = tid; j < PRED_PER_BKT * T_ / 2; j += 256) hist[j] = 0;
    for (int j = tid; j < T_; j += 256) nt_s[j] = gNT[j];
    __syncthreads();

    u32 cnt = gCount[bkt];
    if (cnt > CAP) cnt = CAP;
    const u16* rec = records + (size_t)bkt * CAP;
    for (u32 r = tid; r < cnt; r += 256) {
        u32 v = rec[r];
        atomicAdd(&hist[v >> 1], (v & 1u) ? 65536u : 1u);
    }
    __syncthreads();

    // n_pred: row sums (each group of 16 threads owns one pred row)
    {
        int pl = tid >> 4, lane = tid & 15;
        u32 s = 0;
        for (int w = lane; w < T_ / 2; w += 16) {
            u32 v = hist[pl * (T_ / 2) + w];
            s += (v & 0xFFFFu) + (v >> 16);
        }
        for (int o = 8; o > 0; o >>= 1) s += __shfl_xor(s, o, 16);
        if (lane == 0) npred_s[pl] = (float)s;
    }
    __syncthreads();

    // iou_pc[p][c] = sum_b O/(n_pred + n_tgt - O)
    for (int idx = tid; idx < PRED_PER_BKT * NC; idx += 256) {
        int pl = idx / NC, cls = idx % NC;
        float np = npred_s[pl];
        float acc = 0.f;
        #pragma unroll
        for (int b = 0; b < B_; ++b) {
            int lk = pl * T_ + b * NC + cls;
            u32 w = hist[lk >> 1];
            u32 v = (lk & 1) ? (w >> 16) : (w & 0xFFFFu);
            if (v) {
                float fv = (float)v;
                acc += fv / (np + (float)nt_s[b * NC + cls] - fv);
            }
        }
        iou_pc[pl][cls] = acc;
    }
    __syncthreads();

    // matmul with targets + row-normalize
    for (int pl = 0; pl < PRED_PER_BKT; ++pl) {
        float outc = 0.f;
        if (tid < NC) {
            for (int k = 0; k < NC; ++k) outc += iou_pc[pl][k] * targets[k * NC + tid];
        }
        red[tid] = (tid < NC) ? outc : 0.f;
        __syncthreads();
        for (int o = 128; o > 0; o >>= 1) {
            if (tid < o) red[tid] += red[tid + o];
            __syncthreads();
        }
        float den = red[0];
        __syncthreads();
        if (tid < NC) out[(size_t)(bkt * PRED_PER_BKT + pl) * NC + tid] = outc / den;
    }
}

// ---------------------------------------------------------------------------
extern "C" void kernel_launch(void* const* d_in, const int* in_sizes, int n_in,
                              void* d_out, int out_size, void* d_ws, size_t ws_size,
                              hipStream_t stream) {
    const int*   pred    = (const int*)d_in[0];
    const int*   tgt     = (const int*)d_in[1];
    const float* targets = (const float*)d_in[2];
    float*       out     = (float*)d_out;

    u32* gCount  = (u32*)d_ws;                    // 256
    u32* gNT     = gCount + BUCKETS;              // 2400
    u16* records = (u16*)(gNT + T_);              // 256*18432 u16 = 9.4 MB

    hipMemsetAsync(d_ws, 0, (BUCKETS + T_) * sizeof(u32), stream);

    nt_kernel<<<128, 256, 0, stream>>>(tgt, gNT);
    partition_kernel<<<P1_BLOCKS, 256, 0, stream>>>(pred, tgt, records, gCount);
    iou_kernel<<<BUCKETS, 256, 0, stream>>>(records, gCount, gNT, targets, out);
}

// Round 3
// 69.477 us; speedup vs baseline: 3.4084x; 1.8688x over previous
//
#include <hip/hip_runtime.h>

// Problem constants (fixed by setup_inputs)
#define B_    16
#define N_    262144            // 2^18 pixels per image
#define NC    150               // classes
#define NP    4096              // pred segment ids
#define T_    (B_ * NC)         // 2400 distinct target ids
#define TOTAL (B_ * N_)         // 4,194,304 pixels

#define BUCKETS      256        // pred>>4
#define PRED_PER_BKT 16
#define CAP          18432      // per-bucket record capacity (mean 16384, +16 sigma)
#define P1_BLOCKS    512
#define P1_PIX       (TOTAL / P1_BLOCKS)   // 8192 pixels per block (within ONE image)
#define P1_PER_THR   (P1_PIX / 256)        // 32 per thread

#define Q_PREDS      4          // pred rows per iou co-block
#define QT           (Q_PREDS * T_)        // 9600 local keys per quadrant

typedef unsigned int u32;
typedef unsigned short u16;

// ---------------------------------------------------------------------------
// Kernel 1: radix-split pixels into 256 buckets by pred>>4  (+ fused n_tgt).
// Record = u16 localkey = (p&15)*2400 + (b*150 + cls)  (< 38400, fits u16).
// Each block's 8192 pixels lie in exactly one image -> n_tgt needs only a
// 150-bin LDS histogram flushed with 150 global atomics.
// ---------------------------------------------------------------------------
__global__ __launch_bounds__(256) void partition_kernel(const int* __restrict__ pred,
                                                        const int* __restrict__ tgt,
                                                        u16* __restrict__ records,
                                                        u32* __restrict__ gCount,
                                                        u32* __restrict__ gNT) {
    __shared__ u32 cnt[BUCKETS];
    __shared__ u32 lstart[BUCKETS];
    __shared__ u32 gbase[BUCKETS];
    __shared__ u32 cursor[BUCKETS];
    __shared__ u32 nth[NC];                  // per-image class histogram
    __shared__ u32 staging[P1_PIX];          // 32 KB

    int tid = threadIdx.x;
    cnt[tid] = 0;
    if (tid < NC) nth[tid] = 0;
    __syncthreads();

    u32 keys[P1_PER_THR];
    int base = blockIdx.x * P1_PIX;
    int b_img = base >> 18;                  // constant per block
    const int4* pred4 = (const int4*)pred;
    const int4* tgt4  = (const int4*)tgt;

    #pragma unroll
    for (int k = 0; k < P1_PER_THR / 4; ++k) {
        int vi = (base >> 2) + k * 256 + tid;
        int4 pv = pred4[vi];
        int4 tv = tgt4[vi];
        int pe[4] = {pv.x, pv.y, pv.z, pv.w};
        int te[4] = {tv.x, tv.y, tv.z, tv.w};
        #pragma unroll
        for (int e = 0; e < 4; ++e) {
            int p = pe[e];
            int t = b_img * NC + te[e];
            u32 bkt = (u32)(p >> 4);
            keys[k * 4 + e] = (bkt << 16) | (u32)((p & 15) * T_ + t);
            atomicAdd(&cnt[bkt], 1u);
            atomicAdd(&nth[te[e]], 1u);
        }
    }
    __syncthreads();

    // exclusive prefix sum over 256 bucket counts (Hillis-Steele)
    lstart[tid] = cnt[tid];
    __syncthreads();
    for (int off = 1; off < BUCKETS; off <<= 1) {
        u32 v = 0;
        if (tid >= off) v = lstart[tid - off];
        __syncthreads();
        if (tid >= off) lstart[tid] += v;
        __syncthreads();
    }
    {
        u32 ex = lstart[tid] - cnt[tid];
        lstart[tid] = ex;
        cursor[tid] = ex;
        gbase[tid]  = atomicAdd(&gCount[tid], cnt[tid]);
    }
    if (tid < NC && nth[tid]) atomicAdd(&gNT[b_img * NC + tid], nth[tid]);
    __syncthreads();

    // scatter into LDS staging, sorted by bucket
    #pragma unroll
    for (int k = 0; k < P1_PER_THR; ++k) {
        u32 v = keys[k];
        u32 pos = atomicAdd(&cursor[v >> 16], 1u);
        staging[pos] = v;
    }
    __syncthreads();

    // coalesced flush: runs of ~32 consecutive u16 per bucket
    for (int r = tid; r < P1_PIX; r += 256) {
        u32 v = staging[r];
        u32 bkt = v >> 16;
        u32 gpos = gbase[bkt] + ((u32)r - lstart[bkt]);
        if (gpos < CAP) records[(size_t)bkt * CAP + gpos] = (u16)(v & 0xFFFFu);
    }
}

// ---------------------------------------------------------------------------
// Kernel 2: 4 co-blocks per bucket, each owning 4 pred rows (a "quadrant").
// hist = 4x2400 u16 packed in u32 = 19.2 KB -> ~4 blocks/CU.
// ---------------------------------------------------------------------------
__global__ __launch_bounds__(256, 4) void iou_kernel(const u16* __restrict__ records,
                                                     const u32* __restrict__ gCount,
                                                     const u32* __restrict__ gNT,
                                                     const float* __restrict__ targets,
                                                     float* __restrict__ out) {
    __shared__ u32 hist[QT / 2];              // 4800 words = 19.2 KB
    __shared__ u32 nt_s[T_];                  // 9.6 KB
    __shared__ float npred_s[Q_PREDS];
    __shared__ float iou_pc[Q_PREDS][NC];     // 2.4 KB
    __shared__ float red[256];

    int tid = threadIdx.x;
    int bkt = blockIdx.x >> 2;
    int q   = blockIdx.x & 3;
    u32 lo = (u32)(q * QT), hi = lo + QT;

    for (int j = tid; j < QT / 2; j += 256) hist[j] = 0;
    for (int j = tid; j < T_; j += 256) nt_s[j] = gNT[j];
    __syncthreads();

    u32 cnt = gCount[bkt];
    if (cnt > CAP) cnt = CAP;
    const u16* rec = records + (size_t)bkt * CAP;

    // vectorized scan (8 B/lane), filter to this quadrant
    u32 nv4 = cnt >> 2;
    const ushort4* rec4 = (const ushort4*)rec;
    for (u32 r = tid; r < nv4; r += 256) {
        ushort4 v4 = rec4[r];
        u32 e[4] = {v4.x, v4.y, v4.z, v4.w};
        #pragma unroll
        for (int e_i = 0; e_i < 4; ++e_i) {
            u32 v = e[e_i];
            if (v >= lo && v < hi) {
                u32 lk = v - lo;
                atomicAdd(&hist[lk >> 1], (lk & 1u) ? 65536u : 1u);
            }
        }
    }
    for (u32 r = (nv4 << 2) + tid; r < cnt; r += 256) {
        u32 v = rec[r];
        if (v >= lo && v < hi) {
            u32 lk = v - lo;
            atomicAdd(&hist[lk >> 1], (lk & 1u) ? 65536u : 1u);
        }
    }
    __syncthreads();

    // n_pred row sums: 4 groups of 64 lanes, one pred row each (1200 words)
    {
        int pl = tid >> 6, lane = tid & 63;
        u32 s = 0;
        for (int w = lane; w < T_ / 2; w += 64) {
            u32 v = hist[pl * (T_ / 2) + w];
            s += (v & 0xFFFFu) + (v >> 16);
        }
        #pragma unroll
        for (int o = 32; o > 0; o >>= 1) s += __shfl_xor(s, o);
        if (lane == 0) npred_s[pl] = (float)s;
    }
    __syncthreads();

    // iou_pc[pl][c] = sum_b O/(n_pred + n_tgt - O)
    for (int idx = tid; idx < Q_PREDS * NC; idx += 256) {
        int pl = idx / NC, cls = idx - pl * NC;
        float np = npred_s[pl];
        float acc = 0.f;
        #pragma unroll
        for (int b = 0; b < B_; ++b) {
            int lk = pl * T_ + b * NC + cls;
            u32 w = hist[lk >> 1];
            u32 v = (lk & 1) ? (w >> 16) : (w & 0xFFFFu);
            if (v) {
                float fv = (float)v;
                acc += fv / (np + (float)nt_s[b * NC + cls] - fv);
            }
        }
        iou_pc[pl][cls] = acc;
    }
    __syncthreads();

    // matmul with targets + row-normalize
    for (int pl = 0; pl < Q_PREDS; ++pl) {
        float outc = 0.f;
        if (tid < NC) {
            for (int k = 0; k < NC; ++k) outc += iou_pc[pl][k] * targets[k * NC + tid];
        }
        red[tid] = (tid < NC) ? outc : 0.f;
        __syncthreads();
        for (int o = 128; o > 0; o >>= 1) {
            if (tid < o) red[tid] += red[tid + o];
            __syncthreads();
        }
        float den = red[0];
        __syncthreads();
        if (tid < NC)
            out[(size_t)(bkt * PRED_PER_BKT + q * Q_PREDS + pl) * NC + tid] = outc / den;
    }
}

// ---------------------------------------------------------------------------
extern "C" void kernel_launch(void* const* d_in, const int* in_sizes, int n_in,
                              void* d_out, int out_size, void* d_ws, size_t ws_size,
                              hipStream_t stream) {
    const int*   pred    = (const int*)d_in[0];
    const int*   tgt     = (const int*)d_in[1];
    const float* targets = (const float*)d_in[2];
    float*       out     = (float*)d_out;

    u32* gCount  = (u32*)d_ws;                    // 256
    u32* gNT     = gCount + BUCKETS;              // 2400
    u16* records = (u16*)(gNT + T_);              // 256*18432 u16 = 9.4 MB

    hipMemsetAsync(d_ws, 0, (BUCKETS + T_) * sizeof(u32), stream);

    partition_kernel<<<P1_BLOCKS, 256, 0, stream>>>(pred, tgt, records, gCount, gNT);
    iou_kernel<<<BUCKETS * 4, 256, 0, stream>>>(records, gCount, gNT, targets, out);
}